// Round 1
// baseline (127.549 us; speedup 1.0000x reference)
//
#include <hip/hip_runtime.h>

#define BN_EPS 1e-5f

// Only the center voxel (8,8,8) of the stage-3 output is consumed by the FC
// layer, so we compute exactly the backward-dependency cone:
//   out(8,8,8)  <- x2[15..17]^3 (64ch) <- x1[29..35]^3 (32ch) <- voxel[28..36]^3
// All regions are interior (no zero-padding handling required).
__global__ __launch_bounds__(256) void backbone_center_kernel(
    const float* __restrict__ voxel,
    const float* __restrict__ w1, const float* __restrict__ g1,
    const float* __restrict__ b1, const float* __restrict__ m1, const float* __restrict__ v1,
    const float* __restrict__ w2, const float* __restrict__ g2,
    const float* __restrict__ b2, const float* __restrict__ m2, const float* __restrict__ v2,
    const float* __restrict__ w3, const float* __restrict__ g3,
    const float* __restrict__ b3, const float* __restrict__ m3, const float* __restrict__ v3,
    const float* __restrict__ wp, const float* __restrict__ bp,
    float* __restrict__ out)
{
    const int b   = blockIdx.x;   // batch element
    const int tid = threadIdx.x;  // 256 threads

    __shared__ float s_in[729];     // 9^3 input patch
    __shared__ float s_w1[864];     // 32 x 27 conv1 weights
    __shared__ float s_x1[10976];   // 32 x 7^3 stage-1 activations
    __shared__ float s_x2[1728];    // 64 x 3^3 stage-2 activations
    __shared__ float s_x3[128];     // stage-3 center activations
    __shared__ float sa1[32], ss1[32];
    __shared__ float sa2[64], ss2[64];
    __shared__ float sa3[128], ss3[128];

    // ---- Phase 0: stage input patch + conv1 weights + folded BN constants ----
    const float* vb = voxel + (size_t)b * 64 * 64 * 64;
    for (int i = tid; i < 729; i += 256) {
        int z = i / 81, r = i % 81, y = r / 9, x = r % 9;
        s_in[i] = vb[(28 + z) * 4096 + (28 + y) * 64 + (28 + x)];
    }
    for (int i = tid; i < 864; i += 256) s_w1[i] = w1[i];
    if (tid < 32) {
        float a = g1[tid] * rsqrtf(v1[tid] + BN_EPS);
        sa1[tid] = a; ss1[tid] = b1[tid] - m1[tid] * a;
    } else if (tid >= 64 && tid < 128) {
        int c = tid - 64;
        float a = g2[c] * rsqrtf(v2[c] + BN_EPS);
        sa2[c] = a; ss2[c] = b2[c] - m2[c] * a;
    } else if (tid >= 128) {
        int c = tid - 128;
        float a = g3[c] * rsqrtf(v3[c] + BN_EPS);
        sa3[c] = a; ss3[c] = b3[c] - m3[c] * a;
    }
    __syncthreads();

    // ---- Phase 1: conv1 (stride 1) + BN + ReLU -> s_x1[co][z][y][x], 7^3 ----
    // x1 full-pos q = 29+z reads input full-pos 28+z+kd  -> local z+kd in [0,8]
    for (int t = tid; t < 10976; t += 256) {
        int co = t / 343, r = t % 343;
        int z = r / 49, y = (r / 7) % 7, x = r % 7;
        const float* wc = &s_w1[co * 27];
        float acc = 0.f;
        #pragma unroll
        for (int kd = 0; kd < 3; ++kd)
            #pragma unroll
            for (int kh = 0; kh < 3; ++kh)
                #pragma unroll
                for (int kw = 0; kw < 3; ++kw)
                    acc += s_in[(z + kd) * 81 + (y + kh) * 9 + (x + kw)]
                         * wc[kd * 9 + kh * 3 + kw];
        s_x1[t] = fmaxf(acc * sa1[co] + ss1[co], 0.f);
    }
    __syncthreads();

    // ---- Phase 2: conv2 (stride 2) + BN + ReLU -> s_x2[co][3^3] ----
    // x2 full-pos 15+i reads x1 full-pos 29+2i+kd -> local 2i+kd in [0,6]
    // task order: 27 consecutive lanes share co -> broadcast weight loads
    for (int t = tid; t < 1728; t += 256) {
        int co = t / 27, p = t % 27;
        int i = p / 9, j = (p / 3) % 3, k = p % 3;
        const float* wco = w2 + (size_t)co * 32 * 27;
        float acc = 0.f;
        for (int ci = 0; ci < 32; ++ci) {
            const float* xb = &s_x1[ci * 343 + 2 * i * 49 + 2 * j * 7 + 2 * k];
            const float* wb = wco + ci * 27;
            #pragma unroll
            for (int kd = 0; kd < 3; ++kd)
                #pragma unroll
                for (int kh = 0; kh < 3; ++kh)
                    #pragma unroll
                    for (int kw = 0; kw < 3; ++kw)
                        acc += xb[kd * 49 + kh * 7 + kw] * wb[kd * 9 + kh * 3 + kw];
        }
        s_x2[t] = fmaxf(acc * sa2[co] + ss2[co], 0.f);
    }
    __syncthreads();

    // ---- Phase 3: conv3 (stride 2) center only + BN + ReLU -> s_x3[128] ----
    // out(8,8,8) reads x2 full-pos 15+kd -> local kd: the whole s_x2 tile.
    {
        int co = tid >> 1, half = tid & 1;
        float acc = 0.f;
        const float* wc = w3 + (size_t)co * 64 * 27;
        for (int ci = half * 32; ci < half * 32 + 32; ++ci) {
            const float* xb = &s_x2[ci * 27];
            const float* wb = wc + ci * 27;
            #pragma unroll
            for (int k = 0; k < 27; ++k)
                acc += xb[k] * wb[k];
        }
        acc += __shfl_xor(acc, 1);
        if (half == 0)
            s_x3[co] = fmaxf(acc * sa3[co] + ss3[co], 0.f);
    }
    __syncthreads();

    // ---- Phase 4: FC: out[b][f] = s_x3 . wp[:,f] + bp[f], coalesced over f ----
    {
        float acc = bp[tid];
        for (int ci = 0; ci < 128; ++ci)
            acc += s_x3[ci] * wp[ci * 256 + tid];
        out[b * 256 + tid] = acc;
    }
}

extern "C" void kernel_launch(void* const* d_in, const int* in_sizes, int n_in,
                              void* d_out, int out_size, void* d_ws, size_t ws_size,
                              hipStream_t stream) {
    const float* voxel = (const float*)d_in[0];
    const float* w1 = (const float*)d_in[1];
    const float* g1 = (const float*)d_in[2];
    const float* b1 = (const float*)d_in[3];
    const float* m1 = (const float*)d_in[4];
    const float* v1 = (const float*)d_in[5];
    const float* w2 = (const float*)d_in[6];
    const float* g2 = (const float*)d_in[7];
    const float* b2 = (const float*)d_in[8];
    const float* m2 = (const float*)d_in[9];
    const float* v2 = (const float*)d_in[10];
    const float* w3 = (const float*)d_in[11];
    const float* g3 = (const float*)d_in[12];
    const float* b3 = (const float*)d_in[13];
    const float* m3 = (const float*)d_in[14];
    const float* v3 = (const float*)d_in[15];
    const float* wp = (const float*)d_in[16];
    const float* bp = (const float*)d_in[17];
    float* out = (float*)d_out;

    backbone_center_kernel<<<16, 256, 0, stream>>>(
        voxel, w1, g1, b1, m1, v1, w2, g2, b2, m2, v2,
        w3, g3, b3, m3, v3, wp, bp, out);
}

// Round 2
// 32.527 us; speedup vs baseline: 3.9213x; 3.9213x over previous
//
#include <hip/hip_runtime.h>

#define BN_EPS 1e-5f

// Dependency cone of the single consumed output position (center voxel):
//   out(8,8,8) <- x2[15..17]^3 (64ch) <- x1[29..35]^3 (32ch) <- voxel[28..36]^3
// All interior; no padding logic.
//
// ws layout (floats):
//   ws1 = [16][32][343]   offset 0       (175616 floats, 702 KB)
//   ws2 = [16][64][27]    offset 175616  (27648 floats, 110 KB)

// ---------------- K1: conv1 (stride 1) + BN + ReLU --------------------------
// grid = 16 batches x 8 co-groups (4 co each) = 128 blocks, 256 threads.
__global__ __launch_bounds__(256) void conv1_kernel(
    const float* __restrict__ voxel, const float* __restrict__ w1,
    const float* __restrict__ g1, const float* __restrict__ b1,
    const float* __restrict__ m1, const float* __restrict__ v1,
    float* __restrict__ x1out)
{
    const int b   = blockIdx.x >> 3;
    const int grp = blockIdx.x & 7;      // 4 output channels per block
    const int tid = threadIdx.x;

    __shared__ __align__(16) float s_in[729];   // 9^3 input patch
    __shared__ float s_w[108];                  // 4 x 27
    __shared__ float s_a[4], s_s[4];

    const float* vb = voxel + (size_t)b * 262144;
    for (int i = tid; i < 729; i += 256) {
        int z = i / 81, r = i % 81, y = r / 9, x = r % 9;
        s_in[i] = vb[(28 + z) * 4096 + (28 + y) * 64 + (28 + x)];
    }
    for (int i = tid; i < 108; i += 256) s_w[i] = w1[grp * 108 + i];
    if (tid < 4) {
        int c = grp * 4 + tid;
        float a = g1[c] * rsqrtf(v1[c] + BN_EPS);
        s_a[tid] = a; s_s[tid] = b1[c] - m1[c] * a;
    }
    __syncthreads();

    for (int t = tid; t < 1372; t += 256) {
        int col = t / 343, r = t % 343;
        int z = r / 49, y = (r / 7) % 7, x = r % 7;
        const float* wc = &s_w[col * 27];
        float acc = 0.f;
        #pragma unroll
        for (int kd = 0; kd < 3; ++kd)
        #pragma unroll
        for (int kh = 0; kh < 3; ++kh)
        #pragma unroll
        for (int kw = 0; kw < 3; ++kw)
            acc += s_in[(z + kd) * 81 + (y + kh) * 9 + (x + kw)]
                 * wc[kd * 9 + kh * 3 + kw];
        x1out[(size_t)b * 10976 + grp * 1372 + t] =
            fmaxf(acc * s_a[col] + s_s[col], 0.f);
    }
}

// ---------------- K2: conv2 (stride 2) + BN + ReLU --------------------------
// grid = 16 batches x 8 co-groups (8 co each) = 128 blocks, 256 threads.
// Lane role: col = tid>>5 (local co), ci = tid&31 (input channel).
// LDS x1 addr = 343*ci + const -> bank 23*ci mod 32: bijection, conflict-free.
// Partial sums reduced over ci via 5-step __shfl_xor butterfly.
__global__ __launch_bounds__(256) void conv2_kernel(
    const float* __restrict__ x1in, const float* __restrict__ w2,
    const float* __restrict__ g2, const float* __restrict__ b2,
    const float* __restrict__ m2, const float* __restrict__ v2,
    float* __restrict__ x2out)
{
    const int b   = blockIdx.x >> 3;
    const int grp = blockIdx.x & 7;
    const int tid = threadIdx.x;

    __shared__ __align__(16) float s_x1[10976];   // [ci][7^3]

    const float4* src = (const float4*)(x1in + (size_t)b * 10976);
    float4* dst = (float4*)s_x1;
    for (int i = tid; i < 2744; i += 256) dst[i] = src[i];
    __syncthreads();

    const int col = tid >> 5;            // 0..7 local output channel
    const int ci  = tid & 31;            // input channel owned by this lane
    const int co  = grp * 8 + col;

    // weights for (co, ci): 27 consecutive floats, global -> regs (L2-hit)
    const float* wg = w2 + ((size_t)co * 32 + ci) * 27;
    float wr[27];
    #pragma unroll
    for (int k = 0; k < 27; ++k) wr[k] = wg[k];

    const float* xb = &s_x1[ci * 343];
    float p[27];
    #pragma unroll
    for (int i = 0; i < 3; ++i)
    #pragma unroll
    for (int j = 0; j < 3; ++j)
    #pragma unroll
    for (int k = 0; k < 3; ++k) {
        float acc = 0.f;
        #pragma unroll
        for (int kd = 0; kd < 3; ++kd)
        #pragma unroll
        for (int kh = 0; kh < 3; ++kh)
        #pragma unroll
        for (int kw = 0; kw < 3; ++kw)
            acc += xb[(2*i + kd) * 49 + (2*j + kh) * 7 + (2*k + kw)]
                 * wr[kd * 9 + kh * 3 + kw];
        p[i * 9 + j * 3 + k] = acc;
    }

    #pragma unroll
    for (int q = 0; q < 27; ++q) {
        p[q] += __shfl_xor(p[q], 1);
        p[q] += __shfl_xor(p[q], 2);
        p[q] += __shfl_xor(p[q], 4);
        p[q] += __shfl_xor(p[q], 8);
        p[q] += __shfl_xor(p[q], 16);
    }

    float a = g2[co] * rsqrtf(v2[co] + BN_EPS);
    float s = b2[co] - m2[co] * a;
    #pragma unroll
    for (int q = 0; q < 27; ++q)
        if (ci == q)   // compile-time register index; lane q writes pos q
            x2out[(size_t)b * 1728 + co * 27 + q] = fmaxf(p[q] * a + s, 0.f);
}

// ---------------- K3: conv3 center + BN + ReLU + FC -------------------------
// grid = 16, 256 threads. 16 lane-groups of 16; each group does 8 co.
// w3 per co = 1728 contiguous floats -> coalesced float4 (16 lanes x 16B).
__global__ __launch_bounds__(256) void conv3_fc_kernel(
    const float* __restrict__ x2in, const float* __restrict__ w3,
    const float* __restrict__ g3, const float* __restrict__ b3,
    const float* __restrict__ m3, const float* __restrict__ v3,
    const float* __restrict__ wp, const float* __restrict__ bp,
    float* __restrict__ out)
{
    const int b   = blockIdx.x;
    const int tid = threadIdx.x;

    __shared__ __align__(16) float s_x2[1728];
    __shared__ float s_x3[128];

    const float4* src = (const float4*)(x2in + (size_t)b * 1728);
    float4* dst = (float4*)s_x2;
    for (int i = tid; i < 432; i += 256) dst[i] = src[i];
    __syncthreads();

    const int g = tid >> 4;   // 0..15
    const int j = tid & 15;   // lane within group
    const float4* xv = (const float4*)s_x2;
    #pragma unroll
    for (int cc = 0; cc < 8; ++cc) {
        int co = g * 8 + cc;
        const float4* wv = (const float4*)(w3 + (size_t)co * 1728);
        float acc = 0.f;
        #pragma unroll
        for (int t = 0; t < 27; ++t) {
            float4 w4 = wv[j + 16 * t];
            float4 x4 = xv[j + 16 * t];
            acc += w4.x * x4.x + w4.y * x4.y + w4.z * x4.z + w4.w * x4.w;
        }
        acc += __shfl_xor(acc, 1);
        acc += __shfl_xor(acc, 2);
        acc += __shfl_xor(acc, 4);
        acc += __shfl_xor(acc, 8);
        if (j == 0) {
            float a = g3[co] * rsqrtf(v3[co] + BN_EPS);
            float s = b3[co] - m3[co] * a;
            s_x3[co] = fmaxf(acc * a + s, 0.f);
        }
    }
    __syncthreads();

    // FC: coalesced over output features
    float acc = bp[tid];
    for (int ci = 0; ci < 128; ++ci)
        acc += s_x3[ci] * wp[ci * 256 + tid];
    out[b * 256 + tid] = acc;
}

extern "C" void kernel_launch(void* const* d_in, const int* in_sizes, int n_in,
                              void* d_out, int out_size, void* d_ws, size_t ws_size,
                              hipStream_t stream) {
    const float* voxel = (const float*)d_in[0];
    const float* w1 = (const float*)d_in[1];
    const float* g1 = (const float*)d_in[2];
    const float* b1 = (const float*)d_in[3];
    const float* m1 = (const float*)d_in[4];
    const float* v1 = (const float*)d_in[5];
    const float* w2 = (const float*)d_in[6];
    const float* g2 = (const float*)d_in[7];
    const float* b2 = (const float*)d_in[8];
    const float* m2 = (const float*)d_in[9];
    const float* v2 = (const float*)d_in[10];
    const float* w3 = (const float*)d_in[11];
    const float* g3 = (const float*)d_in[12];
    const float* b3 = (const float*)d_in[13];
    const float* m3 = (const float*)d_in[14];
    const float* v3 = (const float*)d_in[15];
    const float* wp = (const float*)d_in[16];
    const float* bp = (const float*)d_in[17];
    float* out = (float*)d_out;

    float* ws1 = (float*)d_ws;            // 16*32*343 floats
    float* ws2 = ws1 + 16 * 32 * 343;     // 16*64*27 floats

    conv1_kernel<<<128, 256, 0, stream>>>(voxel, w1, g1, b1, m1, v1, ws1);
    conv2_kernel<<<128, 256, 0, stream>>>(ws1, w2, g2, b2, m2, v2, ws2);
    conv3_fc_kernel<<<16, 256, 0, stream>>>(ws2, w3, g3, b3, m3, v3, wp, bp, out);
}